// Round 12
// baseline (75.909 us; speedup 1.0000x reference)
//
#include <hip/hip_runtime.h>

// out[b,h,t,f] = sum_{r=0..64} a[b,h,t,r] * v[b,h, t+r-32, f]  (zero-padded in t)
// B=8 H=16 T=4096 F=64 R=65, fp32 in/out. bf16 MFMA (absmax 0.25 vs thr 1.0).
//
// Round 12 = round 11 + explicit 2-deep v-load pipeline in the MFMA phase.
// r11: FETCH at floor (136MB), occ 79%, but VGPR=32 -> compiler kept only one
// kb-round (8 loads) in flight; MFMA phase serialized on L2 latency. Budget at
// 8 blocks/CU is 64 VGPR (m69: 2048-reg pool / 32 waves). Six named x-arrays
// (static idx, rule #20): kb{0,1} issue before scatter (latency under barriers);
// then issue{2,3}->mfma{0,1}->issue{4,5}->mfma{2,3}->mfma{4,5}: 16 loads in
// flight, each pair covered by 2 MFMAs+converts. Peak ~56 VGPR, no spill.

#define TT 4096
#define RRR 65
#define FF 64
#define SA_S 100     // bf16 row stride: 200B rows -> 2-way (free) on A b128 reads

typedef short bf16x8 __attribute__((ext_vector_type(8)));
typedef float f32x16 __attribute__((ext_vector_type(16)));

__device__ __forceinline__ unsigned short f2bf(float x) {
    unsigned int u = __float_as_uint(x);
    u += 0x7fff + ((u >> 16) & 1);            // RNE
    return (unsigned short)(u >> 16);
}
__device__ __forceinline__ unsigned pk2(float lo, float hi) {
    return (unsigned)f2bf(lo) | ((unsigned)f2bf(hi) << 16);
}

// Barrier with LDS-only drain: global loads/stores stay in flight (no vmcnt).
#define BAR() do {                                                             \
    asm volatile("s_waitcnt lgkmcnt(0)" ::: "memory");                         \
    __builtin_amdgcn_sched_barrier(0);                                         \
    __builtin_amdgcn_s_barrier();                                              \
    __builtin_amdgcn_sched_barrier(0);                                         \
} while (0)

__global__ __launch_bounds__(256, 8)
void unfold_mfma(const float* __restrict__ a, const float* __restrict__ v,
                 float* __restrict__ out) {
    __shared__ __align__(16) unsigned short sa[64 * SA_S];   // 12800 B

    const int tid = threadIdx.x;
    const int f   = tid & 63;
    const int wv  = tid >> 6;
    const int n   = f & 31;
    const int hi  = f >> 5;
    const int wr  = wv >> 1;
    const int wc  = wv & 1;
    const int Rw  = 32 * wr + n;

    // ---- bijective XCD swizzle: each XCD owns 16 whole (b,h) slabs ----
    const int lid = ((blockIdx.x & 7) << 10) | (blockIdx.x >> 3);
    const int bh = lid >> 6;                    // 64 tiles per (b,h)
    const int t0 = (lid & 63) << 6;

    const float* arow = a + ((size_t)bh * TT + t0) * RRR;
    const float* vsl  = v + (size_t)bh * TT * FF;

    const int fcol = 32 * wc + n;
    const int tb   = t0 + 32 * wr - 32 + 8 * hi;   // t for (kb=0, j=0)
    const float* vp = vsl + fcol;
    const bool interior = (t0 >= 32) && (t0 + 96 <= TT);   // 62 of 64 tiles

#define LOADV8(X, KB) do {                                                     \
    if (interior) {                                                            \
        _Pragma("unroll")                                                      \
        for (int j = 0; j < 8; ++j)                                            \
            X[j] = vp[(size_t)(tb + 16 * (KB) + j) * FF];                      \
    } else {                                                                   \
        _Pragma("unroll")                                                      \
        for (int j = 0; j < 8; ++j) {                                          \
            int t = tb + 16 * (KB) + j;                                        \
            X[j] = (t >= 0 && t < TT) ? vp[(size_t)t * FF] : 0.f;              \
        }                                                                      \
    }                                                                          \
} while (0)

#define MFMA1(X, KB) do {                                                      \
    union { bf16x8 v8; unsigned u[4]; } bu_;                                   \
    bu_.u[0] = pk2(X[0], X[1]); bu_.u[1] = pk2(X[2], X[3]);                    \
    bu_.u[2] = pk2(X[4], X[5]); bu_.u[3] = pk2(X[6], X[7]);                    \
    bf16x8 af_ = *(const bf16x8*)&sa[Rw * SA_S + (KB) * 16 + hi * 8];          \
    acc = __builtin_amdgcn_mfma_f32_32x32x16_bf16(af_, bu_.v8, acc, 0, 0, 0);  \
} while (0)

    // ---- issue a loads (aligned quads + edges) ----
    float4 aq[4];
    #pragma unroll
    for (int it = 0; it < 4; ++it) {
        int lin = tid + it * 256;
        if (lin < 64 * 15) {
            int R = lin / 15, j = lin - R * 15;
            int r0 = (4 - (R & 3)) & 3;
            aq[it] = *(const float4*)(arow + (size_t)R * RRR + r0 + 4 * j);
        }
    }
    float ae[2];
    #pragma unroll
    for (int it = 0; it < 2; ++it) {
        int lin = tid + it * 256;
        if (lin < 64 * 5) {
            int R = lin / 5, e = lin - R * 5;
            int r0 = (4 - (R & 3)) & 3;
            int r = (e < r0) ? e : 60 + e;      // head [0,r0) + tail [r0+60,64]
            ae[it] = arow[(size_t)R * RRR + r];
        }
    }

    // ---- v pipeline stage 0: kb {0,1} issued before scatter (latency hides
    //      under prefill + 2 barriers; scatter's vmcnt waits only on older a) ----
    float x0[8], x1[8], x2[8], x3[8], x4[8], x5[8];
    LOADV8(x0, 0);
    LOADV8(x1, 1);

    // ---- zero-prefill sa (band complement must be 0) ----
    {
        uint4 z = make_uint4(0, 0, 0, 0);
        uint4* sp = (uint4*)sa;
        #pragma unroll
        for (int it = 0; it < 4; ++it) {
            int lin = tid + it * 256;
            if (lin < (64 * SA_S) / 8) sp[lin] = z;
        }
    }
    BAR();

    // ---- scatter a band: sa[R][(R&31) + r] = bf16(a[t0+R][r]) ----
    #pragma unroll
    for (int it = 0; it < 4; ++it) {
        int lin = tid + it * 256;
        if (lin < 64 * 15) {
            int R = lin / 15, j = lin - R * 15;
            int r0 = (4 - (R & 3)) & 3;
            int rq = r0 + 4 * j;
            float4 q = aq[it];
            uint2 pw; pw.x = pk2(q.x, q.y); pw.y = pk2(q.z, q.w);
            *(uint2*)&sa[R * SA_S + (R & 31) + rq] = pw;   // (R&31)+rq ≡ 0 mod 4
        }
    }
    #pragma unroll
    for (int it = 0; it < 2; ++it) {
        int lin = tid + it * 256;
        if (lin < 64 * 5) {
            int R = lin / 5, e = lin - R * 5;
            int r0 = (4 - (R & 3)) & 3;
            int r = (e < r0) ? e : 60 + e;
            sa[R * SA_S + (R & 31) + r] = f2bf(ae[it]);
        }
    }
    BAR();

    // ---- MFMA phase, 2-deep pipelined: issue next pair, compute current ----
    f32x16 acc = {};
    LOADV8(x2, 2);
    LOADV8(x3, 3);
    MFMA1(x0, 0);
    MFMA1(x1, 1);
    LOADV8(x4, 4);
    LOADV8(x5, 5);
    MFMA1(x2, 2);
    MFMA1(x3, 3);
    MFMA1(x4, 4);
    MFMA1(x5, 5);

    // ---- store: C/D col = lane&31, row = (reg&3) + 8*(reg>>2) + 4*(lane>>5) ----
    float* op = out + (size_t)bh * TT * FF + (size_t)(t0 + 32 * wr) * FF + 32 * wc;
    #pragma unroll
    for (int reg = 0; reg < 16; ++reg) {
        int row = (reg & 3) + 8 * (reg >> 2) + 4 * hi;
        __builtin_nontemporal_store(acc[reg], &op[row * FF + n]);
    }
}

extern "C" void kernel_launch(void* const* d_in, const int* in_sizes, int n_in,
                              void* d_out, int out_size, void* d_ws, size_t ws_size,
                              hipStream_t stream) {
    const float* a = (const float*)d_in[0];
    const float* v = (const float*)d_in[1];
    float* out = (float*)d_out;

    const int BH = in_sizes[1] / (TT * FF);      // 128
    const int grid = BH * 64;                    // 8192 single-tile blocks

    unfold_mfma<<<grid, 256, 0, stream>>>(a, v, out);
}